// Round 1
// 887.546 us; speedup vs baseline: 1.0096x; 1.0096x over previous
//
#include <hip/hip_runtime.h>
#include <hip/hip_bf16.h>
#include <math.h>

#define Mrows 4096      // B*T
#define Kdim  256       // F
#define Ncols 16384     // G*V
#define Vsz   8192

typedef __attribute__((ext_vector_type(8))) short bf16x8;
typedef __attribute__((ext_vector_type(4))) float f32x4;

// async global->LDS, 16 bytes per lane (dest must be linear: base + lane*16)
#define GLD16(ldsp, gp) __builtin_amdgcn_global_load_lds(                          \
    (const __attribute__((address_space(1))) unsigned int*)(gp),                   \
    (__attribute__((address_space(3))) unsigned int*)(ldsp), 16, 0, 0)

// ---------------- split fp32 -> bf16 (hi, lo) ---------------------------------
__global__ __launch_bounds__(256) void split_bf16(const float* __restrict__ src,
                                                  __hip_bfloat16* __restrict__ hi,
                                                  __hip_bfloat16* __restrict__ lo) {
    const int i = blockIdx.x * 256 + threadIdx.x;
    const float v = src[i];
    const __hip_bfloat16 h = __float2bfloat16(v);
    const float hf = __bfloat162float(h);
    hi[i] = h;
    lo[i] = __float2bfloat16(v - hf);
}

// ---------------- GEMM: hid[m][n] = sum_k A[m][k]*B[n][k] + bias[n] -----------
// split-bf16 3-term MFMA (ah*bh + ah*bl + al*bh), 128x128 tile, BK=32
// staging via global_load_lds width=16 (m97 structure)
__global__ __launch_bounds__(256) void gemm_mfma(const __hip_bfloat16* __restrict__ Ahi,
                                                 const __hip_bfloat16* __restrict__ Alo,
                                                 const __hip_bfloat16* __restrict__ Bhi,
                                                 const __hip_bfloat16* __restrict__ Blo,
                                                 const float* __restrict__ bias,
                                                 float* __restrict__ hid, int r0) {
    __shared__ unsigned short Ah[128 * 32], Al[128 * 32], Bh[128 * 32], Bl[128 * 32];
    const int tid = threadIdx.x;
    const int lane = tid & 63;
    const int wave = tid >> 6;
    const int bm = blockIdx.x * 128;            // chunk-local m tile
    const int bn = blockIdx.y * 128;            // n tile
    const int wm = (wave & 1) * 64;
    const int wn = (wave >> 1) * 64;
    const int lm = lane & 15;                   // row within 16
    const int kq = (lane >> 4) * 8;             // k octet

    f32x4 acc[4][4];
#pragma unroll
    for (int i = 0; i < 4; ++i)
#pragma unroll
        for (int j = 0; j < 4; ++j) acc[i][j] = (f32x4){0.f, 0.f, 0.f, 0.f};

    for (int k0 = 0; k0 < Kdim; k0 += 32) {
        __syncthreads();                        // previous iter's ds_reads done
#pragma unroll
        for (int t = 0; t < 2; ++t) {
            const int c = tid + t * 256;        // 0..511; LDS dest = c*16 bytes (linear)
            const int row = c >> 2;             // 0..127
            const int ko = (c & 3) * 8;         // 0,8,16,24
            const size_t ga = (size_t)(r0 + bm + row) * Kdim + k0 + ko;
            const size_t gb = (size_t)(bn + row) * Kdim + k0 + ko;
            GLD16(&Ah[c * 8], Ahi + ga);
            GLD16(&Al[c * 8], Alo + ga);
            GLD16(&Bh[c * 8], Bhi + gb);
            GLD16(&Bl[c * 8], Blo + gb);
        }
        __syncthreads();                        // compiler drains vmcnt before barrier

        bf16x8 ah[4], al[4], bh[4], bl[4];
#pragma unroll
        for (int i = 0; i < 4; ++i) {
            ah[i] = *(const bf16x8*)&Ah[(wm + i * 16 + lm) * 32 + kq];
            al[i] = *(const bf16x8*)&Al[(wm + i * 16 + lm) * 32 + kq];
            bh[i] = *(const bf16x8*)&Bh[(wn + i * 16 + lm) * 32 + kq];
            bl[i] = *(const bf16x8*)&Bl[(wn + i * 16 + lm) * 32 + kq];
        }
#pragma unroll
        for (int i = 0; i < 4; ++i)
#pragma unroll
            for (int j = 0; j < 4; ++j) {
                acc[i][j] = __builtin_amdgcn_mfma_f32_16x16x32_bf16(ah[i], bh[j], acc[i][j], 0, 0, 0);
                acc[i][j] = __builtin_amdgcn_mfma_f32_16x16x32_bf16(ah[i], bl[j], acc[i][j], 0, 0, 0);
                acc[i][j] = __builtin_amdgcn_mfma_f32_16x16x32_bf16(al[i], bh[j], acc[i][j], 0, 0, 0);
            }
    }

    // epilogue: C/D layout col=lane&15, row=(lane>>4)*4+reg  [m89/m91 verified]
    const int rbase = (lane >> 4) * 4;
#pragma unroll
    for (int j = 0; j < 4; ++j) {
        const int n = bn + wn + j * 16 + lm;
        const float bj = bias[n];
#pragma unroll
        for (int i = 0; i < 4; ++i) {
            const int m0 = bm + wm + i * 16 + rbase;
#pragma unroll
            for (int r2 = 0; r2 < 4; ++r2)
                hid[(size_t)(m0 + r2) * Ncols + n] = acc[i][j][r2] + bj;
        }
    }
}

// ---------------- Phase 2: softmax x2, argmax, codevectors, marginal ----------
// 512 threads, 16 elems/thread via float4; target <=128 VGPR -> 4 waves/SIMD
__global__ __launch_bounds__(512, 4) void phase2(const float* __restrict__ hid,
                                                 const float* __restrict__ u,
                                                 const float* __restrict__ emb,
                                                 const int* __restrict__ mask,
                                                 float* __restrict__ marginal,
                                                 float* __restrict__ out,
                                                 int r0) {
    const int g = blockIdx.y;
    const int n0 = r0 + blockIdx.x * 8;
    const int tid = threadIdx.x;
    const int lane = tid & 63;
    const int wid = tid >> 6;

    __shared__ float marg_s[16 * 512];   // private column per thread (32 KB)
    __shared__ float sv1[8]; __shared__ int si1[8]; __shared__ float sv2[8];
    __shared__ float ss1[8], ss2[8], scv[8][8];

#pragma unroll
    for (int k = 0; k < 16; ++k) marg_s[(k << 9) + tid] = 0.f;

    const float* embg = emb + (size_t)g * Vsz * 8;
    float lg[16];

    for (int r = 0; r < 8; ++r) {
        const int n = n0 + r;
        const float* hrow = hid + (size_t)(n - r0) * Ncols + (size_t)g * Vsz;
        const float* urow = u + ((size_t)n * 2 + g) * Vsz;

        // ---- pass A: noisy logits, running maxes (vectorized float4) ----
        float mx1 = -INFINITY, mx2 = -INFINITY;
        int amax = 0;
#pragma unroll
        for (int i = 0; i < 4; ++i) {
            const int vb = (i << 11) + (tid << 2);          // v base for this chunk
            const float4 hv4 = *(const float4*)(hrow + vb);
            const float4 uu4 = *(const float4*)(urow + vb);
#define GUM(j, hv, uraw) {                                                        \
            float uu = fminf(fmaxf((uraw), 1.17549435e-38f), 1.0f);               \
            const float d = uu - 1.0f;                                            \
            float q = 1.0f / 9.0f;                                                \
            q = fmaf(q, d, -0.125f);                                              \
            q = fmaf(q, d, 1.0f / 7.0f);                                          \
            q = fmaf(q, d, -1.0f / 6.0f);                                         \
            q = fmaf(q, d, 0.2f);                                                 \
            q = fmaf(q, d, -0.25f);                                               \
            q = fmaf(q, d, 1.0f / 3.0f);                                          \
            q = fmaf(q, d, -0.5f);                                                \
            q = fmaf(q, d, 1.0f);                                                 \
            const float inner = (d > -0.2f) ? (-d) * q : -__logf(uu);             \
            const float l = (hv) - __logf(inner);                                 \
            lg[(i << 2) + (j)] = l;                                               \
            if (l > mx1) { mx1 = l; amax = vb + (j); }                            \
            mx2 = fmaxf(mx2, (hv)); }
            GUM(0, hv4.x, uu4.x)
            GUM(1, hv4.y, uu4.y)
            GUM(2, hv4.z, uu4.z)
            GUM(3, hv4.w, uu4.w)
#undef GUM
        }
#pragma unroll
        for (int off = 32; off > 0; off >>= 1) {
            const float ov = __shfl_down(mx1, off);
            const int oi = __shfl_down(amax, off);
            if (ov > mx1 || (ov == mx1 && oi < amax)) { mx1 = ov; amax = oi; }
            mx2 = fmaxf(mx2, __shfl_down(mx2, off));
        }
        if (lane == 0) { sv1[wid] = mx1; si1[wid] = amax; sv2[wid] = mx2; }
        __syncthreads();
        if (tid == 0) {
            float bv = sv1[0]; int bi = si1[0]; float b2 = sv2[0];
            for (int w2 = 1; w2 < 8; ++w2) {
                if (sv1[w2] > bv || (sv1[w2] == bv && si1[w2] < bi)) { bv = sv1[w2]; bi = si1[w2]; }
                b2 = fmaxf(b2, sv2[w2]);
            }
            sv1[0] = bv; si1[0] = bi; sv2[0] = b2;
        }
        __syncthreads();
        const float M1 = sv1[0];
        const float M2 = sv2[0];
        const int AMAX = si1[0];

        // ---- pass B: sums + codevectors; lg[] becomes clean exp terms ----
        float s1 = 0.f, s2 = 0.f;
        float cv[8];
#pragma unroll
        for (int d2 = 0; d2 < 8; ++d2) cv[d2] = 0.f;
#pragma unroll
        for (int i = 0; i < 4; ++i) {
            const int vb = (i << 11) + (tid << 2);
            const float4 hv4 = *(const float4*)(hrow + vb);      // L1/L2 hit
#define PB(j, hv) {                                                               \
            const float p = __expf(lg[(i << 2) + (j)] - M1);                      \
            s1 += p;                                                              \
            const float4 e0 = *(const float4*)(embg + (size_t)(vb + (j)) * 8);    \
            const float4 e1 = *(const float4*)(embg + (size_t)(vb + (j)) * 8 + 4);\
            cv[0] = fmaf(p, e0.x, cv[0]); cv[1] = fmaf(p, e0.y, cv[1]);           \
            cv[2] = fmaf(p, e0.z, cv[2]); cv[3] = fmaf(p, e0.w, cv[3]);           \
            cv[4] = fmaf(p, e1.x, cv[4]); cv[5] = fmaf(p, e1.y, cv[5]);           \
            cv[6] = fmaf(p, e1.z, cv[6]); cv[7] = fmaf(p, e1.w, cv[7]);           \
            const float qq = __expf((hv) - M2);                                   \
            s2 += qq;                                                             \
            lg[(i << 2) + (j)] = qq; }
            PB(0, hv4.x)
            PB(1, hv4.y)
            PB(2, hv4.z)
            PB(3, hv4.w)
#undef PB
        }
#pragma unroll
        for (int off = 32; off > 0; off >>= 1) {
            s1 += __shfl_down(s1, off);
            s2 += __shfl_down(s2, off);
        }
#pragma unroll
        for (int d2 = 0; d2 < 8; ++d2)
#pragma unroll
            for (int off = 32; off > 0; off >>= 1) cv[d2] += __shfl_down(cv[d2], off);
        if (lane == 0) {
            ss1[wid] = s1; ss2[wid] = s2;
#pragma unroll
            for (int d2 = 0; d2 < 8; ++d2) scv[wid][d2] = cv[d2];
        }
        __syncthreads();
        if (tid == 0) {
            float a = 0.f, b = 0.f;
            for (int w2 = 0; w2 < 8; ++w2) { a += ss1[w2]; b += ss2[w2]; }
            ss1[0] = a; ss2[0] = b;
        }
        __syncthreads();
        const float S1 = ss1[0];
        const float S2 = ss2[0];
        if (tid < 8) {
            float c = 0.f;
#pragma unroll
            for (int w2 = 0; w2 < 8; ++w2) c += scv[w2][tid];
            out[(size_t)n * 16 + g * 8 + tid] = c / S1;
        }
        if (tid == 8) out[65537 + (size_t)n * 2 + g] = (float)AMAX;

        if (mask[n] != 0) {
            const float invS2 = 1.0f / S2;
#pragma unroll
            for (int k = 0; k < 16; ++k)
                marg_s[(k << 9) + tid] = fmaf(lg[k], invS2, marg_s[(k << 9) + tid]);
        }
        // no barrier needed here: next row's first LDS writes are gated by its
        // own two barriers before any conflicting array is consumed
    }
#pragma unroll
    for (int k = 0; k < 16; ++k)
        atomicAdd(&marginal[g * Vsz + ((k >> 2) << 11) + (tid << 2) + (k & 3)],
                  marg_s[(k << 9) + tid]);
}

// ---------------- Perplexity --------------------------------------------------
__global__ __launch_bounds__(256) void ppl_kernel(const float* __restrict__ marginal,
                                                  const int* __restrict__ mask,
                                                  float* __restrict__ out) {
    const int tid = threadIdx.x;
    const int lane = tid & 63;
    const int wid = tid >> 6;
    __shared__ float red[4];
    __shared__ int redi[4];

    int ms = 0;
    for (int i = tid; i < Mrows; i += 256) ms += mask[i];
#pragma unroll
    for (int off = 32; off > 0; off >>= 1) ms += __shfl_down(ms, off);
    if (lane == 0) redi[wid] = ms;
    __syncthreads();
    const float inv = 1.0f / (float)(redi[0] + redi[1] + redi[2] + redi[3]);

    float ppl = 0.f;
    for (int g = 0; g < 2; ++g) {
        float part = 0.f;
        for (int v = tid; v < Vsz; v += 256) {
            const float m = marginal[g * Vsz + v] * inv;
            part += m * logf(m + 1e-7f);
        }
#pragma unroll
        for (int off = 32; off > 0; off >>= 1) part += __shfl_down(part, off);
        __syncthreads();
        if (lane == 0) red[wid] = part;
        __syncthreads();
        if (tid == 0) ppl += __expf(-(red[0] + red[1] + red[2] + red[3]));
        __syncthreads();
    }
    if (tid == 0) out[65536] = ppl;
}

// ---------------- Launch ------------------------------------------------------
extern "C" void kernel_launch(void* const* d_in, const int* in_sizes, int n_in,
                              void* d_out, int out_size, void* d_ws, size_t ws_size,
                              hipStream_t stream) {
    const float* x    = (const float*)d_in[0];
    const float* u    = (const float*)d_in[1];
    const float* emb  = (const float*)d_in[2];
    const float* w    = (const float*)d_in[3];
    const float* bias = (const float*)d_in[4];
    const int*   mask = (const int*)d_in[5];
    float* out = (float*)d_out;

    char* base = (char*)d_ws;
    float* marginal = (float*)base;                                    // 64 KB
    __hip_bfloat16* Ahi = (__hip_bfloat16*)(base + 65536);             // 2 MB
    __hip_bfloat16* Alo = Ahi + 1048576;                               // 2 MB
    __hip_bfloat16* Bhi = Alo + 1048576;                               // 8 MB
    __hip_bfloat16* Blo = Bhi + 4194304;                               // 8 MB
    const size_t hid_off = 65536 + 4194304 + 16777216;                 // 21037056
    float* hid = (float*)(base + hid_off);

    size_t cap_rows = (ws_size > hid_off) ? (ws_size - hid_off) / ((size_t)Ncols * 4) : 0;
    int cr = (cap_rows >= Mrows) ? Mrows : (int)((cap_rows / 128) * 128);
    if (cr < 128) cr = 128;

    hipMemsetAsync(marginal, 0, 65536, stream);
    split_bf16<<<4096, 256, 0, stream>>>(x, Ahi, Alo);      // 1M elems
    split_bf16<<<16384, 256, 0, stream>>>(w, Bhi, Blo);     // 4M elems

    for (int r0 = 0; r0 < Mrows; r0 += cr) {
        const int rows = (Mrows - r0 < cr) ? (Mrows - r0) : cr;
        dim3 gg(rows / 128, Ncols / 128);
        gemm_mfma<<<gg, 256, 0, stream>>>(Ahi, Alo, Bhi, Blo, bias, hid, r0);
        dim3 pg(rows / 8, 2);
        phase2<<<pg, 512, 0, stream>>>(hid, u, emb, mask, marginal, out, r0);
    }
    ppl_kernel<<<1, 256, 0, stream>>>(marginal, mask, out);
}